// Round 1
// baseline (1892.865 us; speedup 1.0000x reference)
//
#include <hip/hip_runtime.h>
#include <math.h>

#define BB 8
#define NN 2048
#define DD 128
#define HH 128

// ---------- fast math helpers ----------
__device__ __forceinline__ float fast_rcp(float x) { return __builtin_amdgcn_rcpf(x); }
__device__ __forceinline__ float sigmoidf_(float x) {
    x = fminf(fmaxf(x, -30.f), 30.f);
    return fast_rcp(1.f + __expf(-x));
}
__device__ __forceinline__ float tanhf_(float x) {
    x = fminf(fmaxf(x, -15.f), 15.f);
    float e = __expf(-2.f * x);
    return (1.f - e) * fast_rcp(1.f + e);
}

// ---------------- Kernel 1: graph aggregation ----------------
// xa[b,i,d] = (x[b,i,d] + sum_j a[b,i,j]*x[b,j,d]) / (1 + deg_i)
#define TI 32
#define TJ 64

__global__ __launch_bounds__(256) void k_agg(const float* __restrict__ x,
                                             const int* __restrict__ adj,
                                             float* __restrict__ xa) {
    __shared__ __align__(16) float xs[TJ][132];
    __shared__ __align__(16) float as[TI][68];
    const int b = blockIdx.y;
    const int i0 = blockIdx.x * TI;
    const int tid = threadIdx.x;
    const int ig = tid >> 5;   // 0..7  -> rows ig*4..+3
    const int dg = tid & 31;   // 0..31 -> cols dg*4..+3
    const float* xb = x + (size_t)b * NN * DD;
    const int* ab = adj + (size_t)b * NN * NN;

    float acc[4][4];
    float deg[4];
#pragma unroll
    for (int i = 0; i < 4; ++i) {
        deg[i] = 0.f;
#pragma unroll
        for (int d = 0; d < 4; ++d) acc[i][d] = 0.f;
    }

    for (int j0 = 0; j0 < NN; j0 += TJ) {
        // stage x tile [TJ][128]
#pragma unroll
        for (int k = 0; k < 8; ++k) {
            int idx = tid + k * 256;
            int row = idx >> 5, c4 = idx & 31;
            float4 v = *(const float4*)(xb + (size_t)(j0 + row) * DD + c4 * 4);
            *(float4*)(&xs[row][c4 * 4]) = v;
        }
        // stage adjacency tile [TI][TJ] as float 0/1
#pragma unroll
        for (int k = 0; k < 2; ++k) {
            int idx = tid + k * 256;
            int row = idx >> 4, c4 = idx & 15;
            int4 v = *(const int4*)(ab + (size_t)(i0 + row) * NN + j0 + c4 * 4);
            float4 f;
            f.x = v.x > 0 ? 1.f : 0.f;
            f.y = v.y > 0 ? 1.f : 0.f;
            f.z = v.z > 0 ? 1.f : 0.f;
            f.w = v.w > 0 ? 1.f : 0.f;
            *(float4*)(&as[row][c4 * 4]) = f;
        }
        __syncthreads();
#pragma unroll 4
        for (int jq = 0; jq < TJ; jq += 4) {
            float4 av[4], xv[4];
#pragma unroll
            for (int i = 0; i < 4; ++i) av[i] = *(const float4*)(&as[ig * 4 + i][jq]);
#pragma unroll
            for (int jj = 0; jj < 4; ++jj) xv[jj] = *(const float4*)(&xs[jq + jj][dg * 4]);
#pragma unroll
            for (int i = 0; i < 4; ++i) {
                const float* ap = (const float*)&av[i];
#pragma unroll
                for (int jj = 0; jj < 4; ++jj) {
                    float a = ap[jj];
                    const float* xp4 = (const float*)&xv[jj];
                    deg[i] += a;
                    acc[i][0] = fmaf(a, xp4[0], acc[i][0]);
                    acc[i][1] = fmaf(a, xp4[1], acc[i][1]);
                    acc[i][2] = fmaf(a, xp4[2], acc[i][2]);
                    acc[i][3] = fmaf(a, xp4[3], acc[i][3]);
                }
            }
        }
        __syncthreads();
    }
#pragma unroll
    for (int i = 0; i < 4; ++i) {
        int gi = i0 + ig * 4 + i;
        float r = fast_rcp(1.f + deg[i]);
        float4 xv = *(const float4*)(xb + (size_t)gi * DD + dg * 4);
        float4 o;
        o.x = (xv.x + acc[i][0]) * r;
        o.y = (xv.y + acc[i][1]) * r;
        o.z = (xv.z + acc[i][2]) * r;
        o.w = (xv.w + acc[i][3]) * r;
        *(float4*)(xa + ((size_t)b * NN + gi) * DD + dg * 4) = o;
    }
}

// ---------------- Kernel 2: input projection (both dirs) ----------------
// xp_f[t,b,g] = xa[b,t,:] . w_ih_f[g,:] + (b_ih_f[g]+b_hh_f[g])
// xp_b stored pre-reversed: node t -> slot (NN-1-t)
#define MT 64
#define GT 32

__global__ __launch_bounds__(256) void k_proj(const float* __restrict__ xa,
                                              const float* __restrict__ wif,
                                              const float* __restrict__ wib,
                                              const float* __restrict__ bif,
                                              const float* __restrict__ bhf,
                                              const float* __restrict__ bib,
                                              const float* __restrict__ bhb,
                                              float* __restrict__ xpf,
                                              float* __restrict__ xpb) {
    __shared__ __align__(16) float xs[MT][132];
    __shared__ __align__(16) float wl[GT][132];
    const int r0 = blockIdx.x * MT;
    const int g0 = blockIdx.y * GT;  // 0..1023, fwd gates 0..511, bwd 512..1023
    const int tid = threadIdx.x;
#pragma unroll
    for (int k = 0; k < 8; ++k) {
        int idx = tid + k * 256;
        int row = idx >> 5, c4 = idx & 31;
        int r = r0 + row;
        int t = r >> 3, bb = r & 7;
        float4 v = *(const float4*)(xa + ((size_t)bb * NN + t) * DD + c4 * 4);
        *(float4*)(&xs[row][c4 * 4]) = v;
    }
#pragma unroll
    for (int k = 0; k < 4; ++k) {
        int idx = tid + k * 256;
        int row = idx >> 5, c4 = idx & 31;
        int g = g0 + row;
        const float* wsrc = (g < 512) ? (wif + (size_t)g * DD) : (wib + (size_t)(g - 512) * DD);
        *(float4*)(&wl[row][c4 * 4]) = *(const float4*)(wsrc + c4 * 4);
    }
    __syncthreads();
    const int mg = tid >> 4;  // 0..15 -> rows mg*4..+3
    const int gg = tid & 15;  // 0..15 -> gates gg*2..+1
    float acc[4][2];
#pragma unroll
    for (int i = 0; i < 4; ++i) { acc[i][0] = 0.f; acc[i][1] = 0.f; }
#pragma unroll 8
    for (int d4 = 0; d4 < 32; ++d4) {
        float4 xv[4], wv[2];
#pragma unroll
        for (int i = 0; i < 4; ++i) xv[i] = *(const float4*)(&xs[mg * 4 + i][d4 * 4]);
        wv[0] = *(const float4*)(&wl[gg * 2 + 0][d4 * 4]);
        wv[1] = *(const float4*)(&wl[gg * 2 + 1][d4 * 4]);
#pragma unroll
        for (int i = 0; i < 4; ++i) {
#pragma unroll
            for (int j = 0; j < 2; ++j) {
                acc[i][j] = fmaf(xv[i].x, wv[j].x, acc[i][j]);
                acc[i][j] = fmaf(xv[i].y, wv[j].y, acc[i][j]);
                acc[i][j] = fmaf(xv[i].z, wv[j].z, acc[i][j]);
                acc[i][j] = fmaf(xv[i].w, wv[j].w, acc[i][j]);
            }
        }
    }
#pragma unroll
    for (int j = 0; j < 2; ++j) {
        int g = g0 + gg * 2 + j;
        float bias = (g < 512) ? (bif[g] + bhf[g]) : (bib[g - 512] + bhb[g - 512]);
#pragma unroll
        for (int i = 0; i < 4; ++i) {
            int r = r0 + mg * 4 + i;
            int t = r >> 3, bb = r & 7;
            float v = acc[i][j] + bias;
            if (g < 512)
                xpf[((size_t)t * BB + bb) * 512 + g] = v;
            else
                xpb[((size_t)(NN - 1 - t) * BB + bb) * 512 + (g - 512)] = v;
        }
    }
}

// ---------------- Kernel 3: LSTM recurrence ----------------
// One block per (batch, dir). 512 threads; thread g owns gate row g of W_hh.
__global__ __launch_bounds__(512) void k_lstm(const float* __restrict__ xpf,
                                              const float* __restrict__ xpb,
                                              const float* __restrict__ whf,
                                              const float* __restrict__ whb,
                                              float* __restrict__ out) {
    const int b = blockIdx.x;
    const int dir = blockIdx.y;
    const float* __restrict__ xp = dir ? xpb : xpf;
    const float* __restrict__ wh = dir ? whb : whf;
    const int g = threadIdx.x;  // 0..511

    __shared__ __align__(16) float h_lds[HH];
    __shared__ __align__(16) float gl[512];

    float4 w[32];
#pragma unroll
    for (int k = 0; k < 32; ++k) w[k] = *(const float4*)(wh + (size_t)g * HH + k * 4);

    if (g < HH) h_lds[g] = 0.f;
    __syncthreads();

    float c = 0.f, h = 0.f;
    const int gtype = g >> 7;  // 0:i 1:f 2:g 3:o
    float xpv = xp[(size_t)b * 512 + g];  // t = 0

    for (int t = 0; t < NN; ++t) {
        float xpn = 0.f;
        if (t + 1 < NN) xpn = xp[((size_t)(t + 1) * BB + b) * 512 + g];
        float a0 = xpv, a1 = 0.f, a2 = 0.f, a3 = 0.f;
#pragma unroll
        for (int k = 0; k < 32; k += 4) {
            float4 h0 = *(const float4*)(&h_lds[(k + 0) * 4]);
            float4 h1 = *(const float4*)(&h_lds[(k + 1) * 4]);
            float4 h2 = *(const float4*)(&h_lds[(k + 2) * 4]);
            float4 h3 = *(const float4*)(&h_lds[(k + 3) * 4]);
            a0 = fmaf(w[k + 0].x, h0.x, a0);
            a0 = fmaf(w[k + 0].y, h0.y, a0);
            a0 = fmaf(w[k + 0].z, h0.z, a0);
            a0 = fmaf(w[k + 0].w, h0.w, a0);
            a1 = fmaf(w[k + 1].x, h1.x, a1);
            a1 = fmaf(w[k + 1].y, h1.y, a1);
            a1 = fmaf(w[k + 1].z, h1.z, a1);
            a1 = fmaf(w[k + 1].w, h1.w, a1);
            a2 = fmaf(w[k + 2].x, h2.x, a2);
            a2 = fmaf(w[k + 2].y, h2.y, a2);
            a2 = fmaf(w[k + 2].z, h2.z, a2);
            a2 = fmaf(w[k + 2].w, h2.w, a2);
            a3 = fmaf(w[k + 3].x, h3.x, a3);
            a3 = fmaf(w[k + 3].y, h3.y, a3);
            a3 = fmaf(w[k + 3].z, h3.z, a3);
            a3 = fmaf(w[k + 3].w, h3.w, a3);
        }
        float gate = (a0 + a1) + (a2 + a3);
        float act = (gtype == 2) ? tanhf_(gate) : sigmoidf_(gate);
        gl[g] = act;
        __syncthreads();
        if (g < HH) {
            float iv = gl[g], fv = gl[HH + g], gv = gl[2 * HH + g], ov = gl[3 * HH + g];
            c = fmaf(fv, c, iv * gv);
            h = ov * tanhf_(c);
            h_lds[g] = h;
        }
        __syncthreads();
        xpv = xpn;
    }
    if (g < HH) out[(size_t)b * 256 + dir * HH + g] = h;
}

extern "C" void kernel_launch(void* const* d_in, const int* in_sizes, int n_in,
                              void* d_out, int out_size, void* d_ws, size_t ws_size,
                              hipStream_t stream) {
    const float* x = (const float*)d_in[0];
    const int* adj = (const int*)d_in[1];
    const float* wif = (const float*)d_in[2];
    const float* whf = (const float*)d_in[3];
    const float* bif = (const float*)d_in[4];
    const float* bhf = (const float*)d_in[5];
    const float* wib = (const float*)d_in[6];
    const float* whb = (const float*)d_in[7];
    const float* bib = (const float*)d_in[8];
    const float* bhb = (const float*)d_in[9];
    float* out = (float*)d_out;

    float* xa = (float*)d_ws;                            // [B][N][D]  8.4 MB
    float* xpf = xa + (size_t)BB * NN * DD;              // [N][B][512] 33.5 MB
    float* xpb = xpf + (size_t)NN * BB * 512;            // [N][B][512] 33.5 MB

    k_agg<<<dim3(NN / TI, BB), 256, 0, stream>>>(x, adj, xa);
    k_proj<<<dim3((NN * BB) / MT, 1024 / GT), 256, 0, stream>>>(xa, wif, wib, bif, bhf, bib, bhb,
                                                                xpf, xpb);
    k_lstm<<<dim3(BB, 2), 512, 0, stream>>>(xpf, xpb, whf, whb, out);
}

// Round 2
// 1544.036 us; speedup vs baseline: 1.2259x; 1.2259x over previous
//
#include <hip/hip_runtime.h>
#include <math.h>

#define BB 8
#define NN 2048
#define DD 128
#define HH 128

typedef float f4 __attribute__((ext_vector_type(4)));

// ---------- fast math helpers ----------
__device__ __forceinline__ float fast_rcp(float x) { return __builtin_amdgcn_rcpf(x); }
__device__ __forceinline__ float sigmoidf_(float x) {
    x = fminf(fmaxf(x, -30.f), 30.f);
    return fast_rcp(1.f + __expf(-x));
}
__device__ __forceinline__ float tanhf_(float x) {
    x = fminf(fmaxf(x, -15.f), 15.f);
    float e = __expf(-2.f * x);
    return (1.f - e) * fast_rcp(1.f + e);
}

// DPP quad reduction: sum across the 4 lanes of each aligned quad (pure VALU).
__device__ __forceinline__ float quad_sum(float v) {
    int a = __builtin_amdgcn_update_dpp(0, __float_as_int(v), 0xB1, 0xF, 0xF, true);  // xor 1
    v += __int_as_float(a);
    int b = __builtin_amdgcn_update_dpp(0, __float_as_int(v), 0x4E, 0xF, 0xF, true);  // xor 2
    v += __int_as_float(b);
    return v;
}

// ---------------- Kernel 1: graph aggregation ----------------
#define TI 32
#define TJ 64

__global__ __launch_bounds__(256) void k_agg(const float* __restrict__ x,
                                             const int* __restrict__ adj,
                                             float* __restrict__ xa) {
    __shared__ __align__(16) float xs[TJ][132];
    __shared__ __align__(16) float as[TI][68];
    const int b = blockIdx.y;
    const int i0 = blockIdx.x * TI;
    const int tid = threadIdx.x;
    const int ig = tid >> 5;
    const int dg = tid & 31;
    const float* xb = x + (size_t)b * NN * DD;
    const int* ab = adj + (size_t)b * NN * NN;

    float acc[4][4];
    float deg[4];
#pragma unroll
    for (int i = 0; i < 4; ++i) {
        deg[i] = 0.f;
#pragma unroll
        for (int d = 0; d < 4; ++d) acc[i][d] = 0.f;
    }

    for (int j0 = 0; j0 < NN; j0 += TJ) {
#pragma unroll
        for (int k = 0; k < 8; ++k) {
            int idx = tid + k * 256;
            int row = idx >> 5, c4 = idx & 31;
            float4 v = *(const float4*)(xb + (size_t)(j0 + row) * DD + c4 * 4);
            *(float4*)(&xs[row][c4 * 4]) = v;
        }
#pragma unroll
        for (int k = 0; k < 2; ++k) {
            int idx = tid + k * 256;
            int row = idx >> 4, c4 = idx & 15;
            int4 v = *(const int4*)(ab + (size_t)(i0 + row) * NN + j0 + c4 * 4);
            float4 f;
            f.x = v.x > 0 ? 1.f : 0.f;
            f.y = v.y > 0 ? 1.f : 0.f;
            f.z = v.z > 0 ? 1.f : 0.f;
            f.w = v.w > 0 ? 1.f : 0.f;
            *(float4*)(&as[row][c4 * 4]) = f;
        }
        __syncthreads();
#pragma unroll 4
        for (int jq = 0; jq < TJ; jq += 4) {
            float4 av[4], xv[4];
#pragma unroll
            for (int i = 0; i < 4; ++i) av[i] = *(const float4*)(&as[ig * 4 + i][jq]);
#pragma unroll
            for (int jj = 0; jj < 4; ++jj) xv[jj] = *(const float4*)(&xs[jq + jj][dg * 4]);
#pragma unroll
            for (int i = 0; i < 4; ++i) {
                const float* ap = (const float*)&av[i];
#pragma unroll
                for (int jj = 0; jj < 4; ++jj) {
                    float a = ap[jj];
                    const float* xp4 = (const float*)&xv[jj];
                    deg[i] += a;
                    acc[i][0] = fmaf(a, xp4[0], acc[i][0]);
                    acc[i][1] = fmaf(a, xp4[1], acc[i][1]);
                    acc[i][2] = fmaf(a, xp4[2], acc[i][2]);
                    acc[i][3] = fmaf(a, xp4[3], acc[i][3]);
                }
            }
        }
        __syncthreads();
    }
#pragma unroll
    for (int i = 0; i < 4; ++i) {
        int gi = i0 + ig * 4 + i;
        float r = fast_rcp(1.f + deg[i]);
        float4 xv = *(const float4*)(xb + (size_t)gi * DD + dg * 4);
        float4 o;
        o.x = (xv.x + acc[i][0]) * r;
        o.y = (xv.y + acc[i][1]) * r;
        o.z = (xv.z + acc[i][2]) * r;
        o.w = (xv.w + acc[i][3]) * r;
        *(float4*)(xa + ((size_t)b * NN + gi) * DD + dg * 4) = o;
    }
}

// ---------------- Kernel 2: input projection (both dirs) ----------------
#define MT 64
#define GT 32

__global__ __launch_bounds__(256) void k_proj(const float* __restrict__ xa,
                                              const float* __restrict__ wif,
                                              const float* __restrict__ wib,
                                              const float* __restrict__ bif,
                                              const float* __restrict__ bhf,
                                              const float* __restrict__ bib,
                                              const float* __restrict__ bhb,
                                              float* __restrict__ xpf,
                                              float* __restrict__ xpb) {
    __shared__ __align__(16) float xs[MT][132];
    __shared__ __align__(16) float wl[GT][132];
    const int r0 = blockIdx.x * MT;
    const int g0 = blockIdx.y * GT;
    const int tid = threadIdx.x;
#pragma unroll
    for (int k = 0; k < 8; ++k) {
        int idx = tid + k * 256;
        int row = idx >> 5, c4 = idx & 31;
        int r = r0 + row;
        int t = r >> 3, bb = r & 7;
        float4 v = *(const float4*)(xa + ((size_t)bb * NN + t) * DD + c4 * 4);
        *(float4*)(&xs[row][c4 * 4]) = v;
    }
#pragma unroll
    for (int k = 0; k < 4; ++k) {
        int idx = tid + k * 256;
        int row = idx >> 5, c4 = idx & 31;
        int g = g0 + row;
        const float* wsrc = (g < 512) ? (wif + (size_t)g * DD) : (wib + (size_t)(g - 512) * DD);
        *(float4*)(&wl[row][c4 * 4]) = *(const float4*)(wsrc + c4 * 4);
    }
    __syncthreads();
    const int mg = tid >> 4;
    const int gg = tid & 15;
    float acc[4][2];
#pragma unroll
    for (int i = 0; i < 4; ++i) { acc[i][0] = 0.f; acc[i][1] = 0.f; }
#pragma unroll 8
    for (int d4 = 0; d4 < 32; ++d4) {
        float4 xv[4], wv[2];
#pragma unroll
        for (int i = 0; i < 4; ++i) xv[i] = *(const float4*)(&xs[mg * 4 + i][d4 * 4]);
        wv[0] = *(const float4*)(&wl[gg * 2 + 0][d4 * 4]);
        wv[1] = *(const float4*)(&wl[gg * 2 + 1][d4 * 4]);
#pragma unroll
        for (int i = 0; i < 4; ++i) {
#pragma unroll
            for (int j = 0; j < 2; ++j) {
                acc[i][j] = fmaf(xv[i].x, wv[j].x, acc[i][j]);
                acc[i][j] = fmaf(xv[i].y, wv[j].y, acc[i][j]);
                acc[i][j] = fmaf(xv[i].z, wv[j].z, acc[i][j]);
                acc[i][j] = fmaf(xv[i].w, wv[j].w, acc[i][j]);
            }
        }
    }
#pragma unroll
    for (int j = 0; j < 2; ++j) {
        int g = g0 + gg * 2 + j;
        float bias = (g < 512) ? (bif[g] + bhf[g]) : (bib[g - 512] + bhb[g - 512]);
#pragma unroll
        for (int i = 0; i < 4; ++i) {
            int r = r0 + mg * 4 + i;
            int t = r >> 3, bb = r & 7;
            float v = acc[i][j] + bias;
            if (g < 512)
                xpf[((size_t)t * BB + bb) * 512 + g] = v;
            else
                xpb[((size_t)(NN - 1 - t) * BB + bb) * 512 + (g - 512)] = v;
        }
    }
}

// ---------------- Kernel 3: LSTM recurrence ----------------
// One block per (batch, dir). 512 threads. Thread t finalizes gate t.
// Quad q = t>>2 owns gates 4q..4q+3; lane jq = t&3 computes partials over
// h[32*jq .. 32*jq+31], then DPP quad-reduce. W register-resident (~128 VGPR).
__global__ __launch_bounds__(512, 2) void k_lstm(const float* __restrict__ xpf,
                                                 const float* __restrict__ xpb,
                                                 const float* __restrict__ whf,
                                                 const float* __restrict__ whb,
                                                 float* __restrict__ out) {
    const int b = blockIdx.x;
    const int dir = blockIdx.y;
    const float* __restrict__ xp = dir ? xpb : xpf;
    const float* __restrict__ wh = dir ? whb : whf;
    const int t = threadIdx.x;  // 0..511 == gate id
    const int q = t >> 2;
    const int jq = t & 3;

    __shared__ __align__(16) float h_lds[HH];
    __shared__ __align__(16) float gl[512];

    // Load W rows 4q..4q+3, cols jq*32..+31, k-rotated by 2*jq so the four
    // concurrent 16B LDS reads per instruction land in distinct banks.
    f4 w4[4][8];
#pragma unroll
    for (int g = 0; g < 4; ++g)
#pragma unroll
        for (int k = 0; k < 8; ++k) {
            int col = jq * 32 + (((k + 2 * jq) & 7) << 2);
            w4[g][k] = *(const f4*)(wh + (size_t)(4 * q + g) * HH + col);
        }

    if (t < HH) h_lds[t] = 0.f;
    __syncthreads();

    float c = 0.f, h = 0.f;
    const int gtype = t >> 7;  // 0:i 1:f 2:g 3:o
    float xpv = xp[(size_t)b * 512 + t];  // step = 0

    for (int step = 0; step < NN; ++step) {
        float xpn = 0.f;
        if (step + 1 < NN) xpn = xp[((size_t)(step + 1) * BB + b) * 512 + t];

        f4 h4[8];
#pragma unroll
        for (int k = 0; k < 8; ++k) {
            int col = jq * 32 + (((k + 2 * jq) & 7) << 2);
            h4[k] = *(const f4*)(&h_lds[col]);
        }
        f4 acc0 = {0.f, 0.f, 0.f, 0.f}, acc1 = acc0, acc2 = acc0, acc3 = acc0;
#pragma unroll
        for (int k = 0; k < 8; ++k) {
            acc0 = __builtin_elementwise_fma(w4[0][k], h4[k], acc0);
            acc1 = __builtin_elementwise_fma(w4[1][k], h4[k], acc1);
            acc2 = __builtin_elementwise_fma(w4[2][k], h4[k], acc2);
            acc3 = __builtin_elementwise_fma(w4[3][k], h4[k], acc3);
        }
        float p0 = (acc0.x + acc0.y) + (acc0.z + acc0.w);
        float p1 = (acc1.x + acc1.y) + (acc1.z + acc1.w);
        float p2 = (acc2.x + acc2.y) + (acc2.z + acc2.w);
        float p3 = (acc3.x + acc3.y) + (acc3.z + acc3.w);
        p0 = quad_sum(p0);
        p1 = quad_sum(p1);
        p2 = quad_sum(p2);
        p3 = quad_sum(p3);
        float pa = (jq & 1) ? p1 : p0;
        float pb_ = (jq & 1) ? p3 : p2;
        float gate = ((jq & 2) ? pb_ : pa) + xpv;
        float act = (gtype == 2) ? tanhf_(gate) : sigmoidf_(gate);
        gl[t] = act;
        __syncthreads();
        if (t < HH) {
            float iv = gl[t], fv = gl[HH + t], gv = gl[2 * HH + t], ov = gl[3 * HH + t];
            c = fmaf(fv, c, iv * gv);
            h = ov * tanhf_(c);
            h_lds[t] = h;
        }
        __syncthreads();
        xpv = xpn;
    }
    if (t < HH) out[(size_t)b * 256 + dir * HH + t] = h;
}

extern "C" void kernel_launch(void* const* d_in, const int* in_sizes, int n_in,
                              void* d_out, int out_size, void* d_ws, size_t ws_size,
                              hipStream_t stream) {
    const float* x = (const float*)d_in[0];
    const int* adj = (const int*)d_in[1];
    const float* wif = (const float*)d_in[2];
    const float* whf = (const float*)d_in[3];
    const float* bif = (const float*)d_in[4];
    const float* bhf = (const float*)d_in[5];
    const float* wib = (const float*)d_in[6];
    const float* whb = (const float*)d_in[7];
    const float* bib = (const float*)d_in[8];
    const float* bhb = (const float*)d_in[9];
    float* out = (float*)d_out;

    float* xa = (float*)d_ws;                            // [B][N][D]
    float* xpf = xa + (size_t)BB * NN * DD;              // [N][B][512]
    float* xpb = xpf + (size_t)NN * BB * 512;            // [N][B][512]

    k_agg<<<dim3(NN / TI, BB), 256, 0, stream>>>(x, adj, xa);
    k_proj<<<dim3((NN * BB) / MT, 1024 / GT), 256, 0, stream>>>(xa, wif, wib, bif, bhf, bib, bhb,
                                                                xpf, xpb);
    k_lstm<<<dim3(BB, 2), 512, 0, stream>>>(xpf, xpb, whf, whb, out);
}

// Round 3
// 1521.007 us; speedup vs baseline: 1.2445x; 1.0151x over previous
//
#include <hip/hip_runtime.h>
#include <math.h>

#define BB 8
#define NN 2048
#define DD 128
#define HH 128

typedef float f4 __attribute__((ext_vector_type(4)));

// ---------- fast math helpers ----------
__device__ __forceinline__ float fast_rcp(float x) { return __builtin_amdgcn_rcpf(x); }
__device__ __forceinline__ float sigmoidf_(float x) {
    x = fminf(fmaxf(x, -30.f), 30.f);
    return fast_rcp(1.f + __expf(-x));
}
__device__ __forceinline__ float tanhf_(float x) {
    x = fminf(fmaxf(x, -15.f), 15.f);
    float e = __expf(-2.f * x);
    return (1.f - e) * fast_rcp(1.f + e);
}

// DPP quad reduction: sum across the 4 lanes of each aligned quad (pure VALU).
__device__ __forceinline__ float quad_sum(float v) {
    int a = __builtin_amdgcn_update_dpp(0, __float_as_int(v), 0xB1, 0xF, 0xF, true);  // xor 1
    v += __int_as_float(a);
    int b = __builtin_amdgcn_update_dpp(0, __float_as_int(v), 0x4E, 0xF, 0xF, true);  // xor 2
    v += __int_as_float(b);
    return v;
}

// ---------------- Kernel 1: graph aggregation ----------------
#define TI 32
#define TJ 64

__global__ __launch_bounds__(256) void k_agg(const float* __restrict__ x,
                                             const int* __restrict__ adj,
                                             float* __restrict__ xa) {
    __shared__ __align__(16) float xs[TJ][132];
    __shared__ __align__(16) float as[TI][68];
    const int b = blockIdx.y;
    const int i0 = blockIdx.x * TI;
    const int tid = threadIdx.x;
    const int ig = tid >> 5;
    const int dg = tid & 31;
    const float* xb = x + (size_t)b * NN * DD;
    const int* ab = adj + (size_t)b * NN * NN;

    float acc[4][4];
    float deg[4];
#pragma unroll
    for (int i = 0; i < 4; ++i) {
        deg[i] = 0.f;
#pragma unroll
        for (int d = 0; d < 4; ++d) acc[i][d] = 0.f;
    }

    for (int j0 = 0; j0 < NN; j0 += TJ) {
#pragma unroll
        for (int k = 0; k < 8; ++k) {
            int idx = tid + k * 256;
            int row = idx >> 5, c4 = idx & 31;
            float4 v = *(const float4*)(xb + (size_t)(j0 + row) * DD + c4 * 4);
            *(float4*)(&xs[row][c4 * 4]) = v;
        }
#pragma unroll
        for (int k = 0; k < 2; ++k) {
            int idx = tid + k * 256;
            int row = idx >> 4, c4 = idx & 15;
            int4 v = *(const int4*)(ab + (size_t)(i0 + row) * NN + j0 + c4 * 4);
            float4 f;
            f.x = v.x > 0 ? 1.f : 0.f;
            f.y = v.y > 0 ? 1.f : 0.f;
            f.z = v.z > 0 ? 1.f : 0.f;
            f.w = v.w > 0 ? 1.f : 0.f;
            *(float4*)(&as[row][c4 * 4]) = f;
        }
        __syncthreads();
#pragma unroll 4
        for (int jq = 0; jq < TJ; jq += 4) {
            float4 av[4], xv[4];
#pragma unroll
            for (int i = 0; i < 4; ++i) av[i] = *(const float4*)(&as[ig * 4 + i][jq]);
#pragma unroll
            for (int jj = 0; jj < 4; ++jj) xv[jj] = *(const float4*)(&xs[jq + jj][dg * 4]);
#pragma unroll
            for (int i = 0; i < 4; ++i) {
                const float* ap = (const float*)&av[i];
#pragma unroll
                for (int jj = 0; jj < 4; ++jj) {
                    float a = ap[jj];
                    const float* xp4 = (const float*)&xv[jj];
                    deg[i] += a;
                    acc[i][0] = fmaf(a, xp4[0], acc[i][0]);
                    acc[i][1] = fmaf(a, xp4[1], acc[i][1]);
                    acc[i][2] = fmaf(a, xp4[2], acc[i][2]);
                    acc[i][3] = fmaf(a, xp4[3], acc[i][3]);
                }
            }
        }
        __syncthreads();
    }
#pragma unroll
    for (int i = 0; i < 4; ++i) {
        int gi = i0 + ig * 4 + i;
        float r = fast_rcp(1.f + deg[i]);
        float4 xv = *(const float4*)(xb + (size_t)gi * DD + dg * 4);
        float4 o;
        o.x = (xv.x + acc[i][0]) * r;
        o.y = (xv.y + acc[i][1]) * r;
        o.z = (xv.z + acc[i][2]) * r;
        o.w = (xv.w + acc[i][3]) * r;
        *(float4*)(xa + ((size_t)b * NN + gi) * DD + dg * 4) = o;
    }
}

// ---------------- Kernel 2: input projection (both dirs) ----------------
#define MT 64
#define GT 32

__global__ __launch_bounds__(256) void k_proj(const float* __restrict__ xa,
                                              const float* __restrict__ wif,
                                              const float* __restrict__ wib,
                                              const float* __restrict__ bif,
                                              const float* __restrict__ bhf,
                                              const float* __restrict__ bib,
                                              const float* __restrict__ bhb,
                                              float* __restrict__ xpf,
                                              float* __restrict__ xpb) {
    __shared__ __align__(16) float xs[MT][132];
    __shared__ __align__(16) float wl[GT][132];
    const int r0 = blockIdx.x * MT;
    const int g0 = blockIdx.y * GT;
    const int tid = threadIdx.x;
#pragma unroll
    for (int k = 0; k < 8; ++k) {
        int idx = tid + k * 256;
        int row = idx >> 5, c4 = idx & 31;
        int r = r0 + row;
        int t = r >> 3, bb = r & 7;
        float4 v = *(const float4*)(xa + ((size_t)bb * NN + t) * DD + c4 * 4);
        *(float4*)(&xs[row][c4 * 4]) = v;
    }
#pragma unroll
    for (int k = 0; k < 4; ++k) {
        int idx = tid + k * 256;
        int row = idx >> 5, c4 = idx & 31;
        int g = g0 + row;
        const float* wsrc = (g < 512) ? (wif + (size_t)g * DD) : (wib + (size_t)(g - 512) * DD);
        *(float4*)(&wl[row][c4 * 4]) = *(const float4*)(wsrc + c4 * 4);
    }
    __syncthreads();
    const int mg = tid >> 4;
    const int gg = tid & 15;
    float acc[4][2];
#pragma unroll
    for (int i = 0; i < 4; ++i) { acc[i][0] = 0.f; acc[i][1] = 0.f; }
#pragma unroll 8
    for (int d4 = 0; d4 < 32; ++d4) {
        float4 xv[4], wv[2];
#pragma unroll
        for (int i = 0; i < 4; ++i) xv[i] = *(const float4*)(&xs[mg * 4 + i][d4 * 4]);
        wv[0] = *(const float4*)(&wl[gg * 2 + 0][d4 * 4]);
        wv[1] = *(const float4*)(&wl[gg * 2 + 1][d4 * 4]);
#pragma unroll
        for (int i = 0; i < 4; ++i) {
#pragma unroll
            for (int j = 0; j < 2; ++j) {
                acc[i][j] = fmaf(xv[i].x, wv[j].x, acc[i][j]);
                acc[i][j] = fmaf(xv[i].y, wv[j].y, acc[i][j]);
                acc[i][j] = fmaf(xv[i].z, wv[j].z, acc[i][j]);
                acc[i][j] = fmaf(xv[i].w, wv[j].w, acc[i][j]);
            }
        }
    }
#pragma unroll
    for (int j = 0; j < 2; ++j) {
        int g = g0 + gg * 2 + j;
        float bias = (g < 512) ? (bif[g] + bhf[g]) : (bib[g - 512] + bhb[g - 512]);
#pragma unroll
        for (int i = 0; i < 4; ++i) {
            int r = r0 + mg * 4 + i;
            int t = r >> 3, bb = r & 7;
            float v = acc[i][j] + bias;
            if (g < 512)
                xpf[((size_t)t * BB + bb) * 512 + g] = v;
            else
                xpb[((size_t)(NN - 1 - t) * BB + bb) * 512 + (g - 512)] = v;
        }
    }
}

// ---------------- Kernel 3: LSTM recurrence ----------------
// One block per (batch, dir). 512 threads. Thread t finalizes gate t.
// Quad q = t>>2 owns gates 4q..4q+3; lane jq = t&3 computes partials over
// h[32*jq .. 32*jq+31], then DPP quad-reduce.
// amdgpu_waves_per_eu(2,2): grid is 16 blocks (1/CU max) so real occupancy is
// 2 waves/SIMD regardless; clamping max=2 gives the allocator the full 256-VGPR
// budget so the 128-VGPR W slice stays register-resident instead of being
// re-loaded from L2 every timestep (R2: VGPR_Count=84 = 512/6-wave target).
__global__ __attribute__((amdgpu_flat_work_group_size(512, 512), amdgpu_waves_per_eu(2, 2)))
void k_lstm(const float* __restrict__ xpf,
            const float* __restrict__ xpb,
            const float* __restrict__ whf,
            const float* __restrict__ whb,
            float* __restrict__ out) {
    const int b = blockIdx.x;
    const int dir = blockIdx.y;
    const float* __restrict__ xp = dir ? xpb : xpf;
    const float* __restrict__ wh = dir ? whb : whf;
    const int t = threadIdx.x;  // 0..511 == gate id
    const int q = t >> 2;
    const int jq = t & 3;

    __shared__ __align__(16) float h_lds[HH];
    __shared__ __align__(16) float gl[512];

    // Load W rows 4q..4q+3, cols jq*32..+31, k-rotated by 2*jq so the four
    // concurrent 16B LDS reads per instruction land in distinct banks.
    f4 w4[4][8];
#pragma unroll
    for (int g = 0; g < 4; ++g)
#pragma unroll
        for (int k = 0; k < 8; ++k) {
            int col = jq * 32 + (((k + 2 * jq) & 7) << 2);
            w4[g][k] = *(const f4*)(wh + (size_t)(4 * q + g) * HH + col);
        }

    if (t < HH) h_lds[t] = 0.f;
    __syncthreads();

    float c = 0.f, h = 0.f;
    const int gtype = t >> 7;  // 0:i 1:f 2:g 3:o
    float xpv = xp[(size_t)b * 512 + t];  // step = 0

    for (int step = 0; step < NN; ++step) {
        float xpn = 0.f;
        if (step + 1 < NN) xpn = xp[((size_t)(step + 1) * BB + b) * 512 + t];

        f4 h4[8];
#pragma unroll
        for (int k = 0; k < 8; ++k) {
            int col = jq * 32 + (((k + 2 * jq) & 7) << 2);
            h4[k] = *(const f4*)(&h_lds[col]);
        }
        f4 acc0 = {0.f, 0.f, 0.f, 0.f}, acc1 = acc0, acc2 = acc0, acc3 = acc0;
#pragma unroll
        for (int k = 0; k < 8; ++k) {
            acc0 = __builtin_elementwise_fma(w4[0][k], h4[k], acc0);
            acc1 = __builtin_elementwise_fma(w4[1][k], h4[k], acc1);
            acc2 = __builtin_elementwise_fma(w4[2][k], h4[k], acc2);
            acc3 = __builtin_elementwise_fma(w4[3][k], h4[k], acc3);
        }
        float p0 = (acc0.x + acc0.y) + (acc0.z + acc0.w);
        float p1 = (acc1.x + acc1.y) + (acc1.z + acc1.w);
        float p2 = (acc2.x + acc2.y) + (acc2.z + acc2.w);
        float p3 = (acc3.x + acc3.y) + (acc3.z + acc3.w);
        p0 = quad_sum(p0);
        p1 = quad_sum(p1);
        p2 = quad_sum(p2);
        p3 = quad_sum(p3);
        float pa = (jq & 1) ? p1 : p0;
        float pb_ = (jq & 1) ? p3 : p2;
        float gate = ((jq & 2) ? pb_ : pa) + xpv;
        float act = (gtype == 2) ? tanhf_(gate) : sigmoidf_(gate);
        gl[t] = act;
        __syncthreads();
        if (t < HH) {
            float iv = gl[t], fv = gl[HH + t], gv = gl[2 * HH + t], ov = gl[3 * HH + t];
            c = fmaf(fv, c, iv * gv);
            h = ov * tanhf_(c);
            h_lds[t] = h;
        }
        __syncthreads();
        xpv = xpn;
    }
    if (t < HH) out[(size_t)b * 256 + dir * HH + t] = h;
}

extern "C" void kernel_launch(void* const* d_in, const int* in_sizes, int n_in,
                              void* d_out, int out_size, void* d_ws, size_t ws_size,
                              hipStream_t stream) {
    const float* x = (const float*)d_in[0];
    const int* adj = (const int*)d_in[1];
    const float* wif = (const float*)d_in[2];
    const float* whf = (const float*)d_in[3];
    const float* bif = (const float*)d_in[4];
    const float* bhf = (const float*)d_in[5];
    const float* wib = (const float*)d_in[6];
    const float* whb = (const float*)d_in[7];
    const float* bib = (const float*)d_in[8];
    const float* bhb = (const float*)d_in[9];
    float* out = (float*)d_out;

    float* xa = (float*)d_ws;                            // [B][N][D]
    float* xpf = xa + (size_t)BB * NN * DD;              // [N][B][512]
    float* xpb = xpf + (size_t)NN * BB * 512;            // [N][B][512]

    k_agg<<<dim3(NN / TI, BB), 256, 0, stream>>>(x, adj, xa);
    k_proj<<<dim3((NN * BB) / MT, 1024 / GT), 256, 0, stream>>>(xa, wif, wib, bif, bhf, bib, bhb,
                                                                xpf, xpb);
    k_lstm<<<dim3(BB, 2), 512, 0, stream>>>(xpf, xpb, whf, whb, out);
}